// Round 5
// baseline (3303.357 us; speedup 1.0000x reference)
//
#include <hip/hip_runtime.h>

#define BT   8      // batch tile per block
#define HID  64
#define G4   256    // 4*HID
#define SEQ  512
#define NOUT 12
#define NT   768    // 3 groups x 256 gate rows

typedef float v16f __attribute__((ext_vector_type(16)));

__device__ __forceinline__ float sigf(float x)  { return 1.f / (1.f + __expf(-x)); }
__device__ __forceinline__ float tanhf_fast(float x) { return 1.f - 2.f / (1.f + __expf(2.f * x)); }

__global__ void __launch_bounds__(NT) __attribute__((amdgpu_waves_per_eu(3, 3)))
lstm2_fused(
    const float* __restrict__ x,      // [B, SEQ, 1]
    const float* __restrict__ w_ih0,  // [256, 1]
    const float* __restrict__ w_hh0,  // [256, 64]
    const float* __restrict__ b_ih0,  // [256]
    const float* __restrict__ b_hh0,  // [256]
    const float* __restrict__ w_ih1,  // [256, 64]
    const float* __restrict__ w_hh1,  // [256, 64]
    const float* __restrict__ b_ih1,  // [256]
    const float* __restrict__ b_hh1,  // [256]
    const float* __restrict__ fc_w,   // [12, 64]
    const float* __restrict__ fc_b,   // [12]
    float* __restrict__ out)          // [B, 12]
{
    __shared__ float xs[BT][SEQ];    // 16 KB
    __shared__ float h0s[BT][HID];   // 2 KB
    __shared__ float h1s[BT][HID];   // 2 KB
    __shared__ float gs0[BT][G4];    // 8 KB  layer-0 gates
    __shared__ float gsB[BT][G4];    // 8 KB  w_ih1 . h0 partial
    __shared__ float gsC[BT][G4];    // 8 KB  w_hh1 . h1 partial

    const int tid = threadIdx.x;
    const int grp = tid >> 8;         // 0: w_hh0 | 1: w_ih1 | 2: w_hh1
    const int g   = tid & 255;        // gate row owned by this thread
    const int b0  = blockIdx.x * BT;

    // ---- this thread's 64-float weight row as 4 SSA v16f (64 VGPRs) ----
    const float* wrow = (grp == 0) ? &w_hh0[g * HID]
                      : (grp == 1) ? &w_ih1[g * HID]
                                   : &w_hh1[g * HID];
    v16f w0 = {}, w1 = {}, w2 = {}, w3 = {};
#pragma unroll
    for (int c = 0; c < 4; ++c) {
        v16f& W = (c == 0) ? w0 : (c == 1) ? w1 : (c == 2) ? w2 : w3;
#pragma unroll
        for (int j = 0; j < 4; ++j) {
            float4 q = ((const float4*)wrow)[c * 4 + j];
            W[4*j+0] = q.x; W[4*j+1] = q.y; W[4*j+2] = q.z; W[4*j+3] = q.w;
        }
    }
    const float binit = (grp == 0) ? (b_ih0[g] + b_hh0[g])
                      : (grp == 1) ? (b_ih1[g] + b_hh1[g]) : 0.f;
    const float wx = (grp == 0) ? w_ih0[g] : 0.f;     // input size == 1

    // which h-vector this group's GEMV consumes, and where partials go
    float (*hs)[HID] = (grp == 2) ? h1s : h0s;
    float (*gsw)[G4] = (grp == 0) ? gs0 : (grp == 1) ? gsB : gsC;

    // ---- stage x tile, zero h state ----
    for (int i = tid; i < BT * SEQ; i += NT) {
        int b = i >> 9, t = i & (SEQ - 1);
        xs[b][t] = x[(size_t)(b0 + b) * SEQ + t];
    }
    for (int i = tid; i < BT * HID; i += NT) {
        ((float*)h0s)[i] = 0.f;
        ((float*)h1s)[i] = 0.f;
    }
    // elementwise identities
    const int eb = (tid >> 6) & 7;   // ew0: batch (threads 0..511)
    const int ej = tid & 63;         // hidden unit
    const int cb = (tid >> 6) & 3;   // ew1: base batch (threads 512..767, 2 units)
    float c0 = 0.f, c1a = 0.f, c1b = 0.f;
    __syncthreads();

    // Pipelined: iter i computes layer0(t=i) and layer1(t=i-1) concurrently.
    for (int i = 0; i <= SEQ; ++i) {
        // ===== phase 1: three GEMVs in parallel (one per group) =====
        const bool active = (grp == 0) ? (i < SEQ) : (i >= 1);
        if (active) {
            float a[BT];
#pragma unroll
            for (int b = 0; b < BT; ++b) a[b] = binit;
            if (grp == 0) {
#pragma unroll
                for (int b = 0; b < BT; ++b) a[b] = fmaf(xs[b][i], wx, a[b]);
            }
#pragma unroll
            for (int c = 0; c < 4; ++c) {
                const v16f& W = (c == 0) ? w0 : (c == 1) ? w1 : (c == 2) ? w2 : w3;
#pragma unroll
                for (int q = 0; q < 4; ++q) {
#pragma unroll
                    for (int b = 0; b < BT; ++b) {
                        float4 hv = *(const float4*)&hs[b][c * 16 + q * 4]; // uniform broadcast
                        a[b] = fmaf(hv.x, W[q*4+0], a[b]);
                        a[b] = fmaf(hv.y, W[q*4+1], a[b]);
                        a[b] = fmaf(hv.z, W[q*4+2], a[b]);
                        a[b] = fmaf(hv.w, W[q*4+3], a[b]);
                    }
                }
            }
#pragma unroll
            for (int b = 0; b < BT; ++b) gsw[b][g] = a[b];
        }
        __syncthreads();

        // ===== phase 2: elementwise for both layers in parallel =====
        if (tid < BT * HID) {                 // 512 threads: layer-0 ew at t=i
            if (i < SEQ) {
                float ig = sigf(gs0[eb][ej]);
                float fg = sigf(gs0[eb][64 + ej]);
                float gg = tanhf_fast(gs0[eb][128 + ej]);
                float og = sigf(gs0[eb][192 + ej]);
                c0 = fg * c0 + ig * gg;
                h0s[eb][ej] = og * tanhf_fast(c0);
            }
        } else {                              // 256 threads: layer-1 ew at t=i-1 (2 units)
            if (i >= 1) {
                {
                    int b = cb;
                    float ig = sigf(gsB[b][ej]        + gsC[b][ej]);
                    float fg = sigf(gsB[b][64 + ej]   + gsC[b][64 + ej]);
                    float gg = tanhf_fast(gsB[b][128 + ej] + gsC[b][128 + ej]);
                    float og = sigf(gsB[b][192 + ej]  + gsC[b][192 + ej]);
                    c1a = fg * c1a + ig * gg;
                    h1s[b][ej] = og * tanhf_fast(c1a);
                }
                {
                    int b = cb + 4;
                    float ig = sigf(gsB[b][ej]        + gsC[b][ej]);
                    float fg = sigf(gsB[b][64 + ej]   + gsC[b][64 + ej]);
                    float gg = tanhf_fast(gsB[b][128 + ej] + gsC[b][128 + ej]);
                    float og = sigf(gsB[b][192 + ej]  + gsC[b][192 + ej]);
                    c1b = fg * c1b + ig * gg;
                    h1s[b][ej] = og * tanhf_fast(c1b);
                }
            }
        }
        __syncthreads();
    }

    // ===== final projection: out[b][o] = fc_b[o] + h1 . fc_w[o] =====
    if (tid < BT * NOUT) {
        int b = tid / NOUT, o = tid % NOUT;
        float acc = fc_b[o];
#pragma unroll
        for (int j = 0; j < HID; ++j)
            acc = fmaf(fc_w[o * HID + j], h1s[b][j], acc);
        out[(size_t)(b0 + b) * NOUT + o] = acc;
    }
}

extern "C" void kernel_launch(void* const* d_in, const int* in_sizes, int n_in,
                              void* d_out, int out_size, void* d_ws, size_t ws_size,
                              hipStream_t stream) {
    const float* x     = (const float*)d_in[0];
    const float* w_ih0 = (const float*)d_in[1];
    const float* w_hh0 = (const float*)d_in[2];
    const float* b_ih0 = (const float*)d_in[3];
    const float* b_hh0 = (const float*)d_in[4];
    const float* w_ih1 = (const float*)d_in[5];
    const float* w_hh1 = (const float*)d_in[6];
    const float* b_ih1 = (const float*)d_in[7];
    const float* b_hh1 = (const float*)d_in[8];
    const float* fc_w  = (const float*)d_in[9];
    const float* fc_b  = (const float*)d_in[10];

    const int B = in_sizes[0] / SEQ;          // 2048
    dim3 grid(B / BT);                        // 256 blocks -> 1 block/CU
    lstm2_fused<<<grid, NT, 0, stream>>>(x, w_ih0, w_hh0, b_ih0, b_hh0,
                                         w_ih1, w_hh1, b_ih1, b_hh1,
                                         fc_w, fc_b, (float*)d_out);
}

// Round 6
// 2093.728 us; speedup vs baseline: 1.5777x; 1.5777x over previous
//
#include <hip/hip_runtime.h>

#define BT   4      // batch tile per block
#define HID  64
#define G4   256    // 4*HID
#define SEQ  512
#define NOUT 12

typedef float v4f __attribute__((ext_vector_type(4)));

__device__ __forceinline__ float sigf(float x)  { return 1.f / (1.f + __expf(-x)); }
__device__ __forceinline__ float tanhf_fast(float x) { return 1.f - 2.f / (1.f + __expf(2.f * x)); }

__global__ void __launch_bounds__(256) __attribute__((amdgpu_waves_per_eu(2, 2)))
lstm2_fused(
    const float* __restrict__ x,      // [B, SEQ, 1]
    const float* __restrict__ w_ih0,  // [256, 1]
    const float* __restrict__ w_hh0,  // [256, 64]
    const float* __restrict__ b_ih0,  // [256]
    const float* __restrict__ b_hh0,  // [256]
    const float* __restrict__ w_ih1,  // [256, 64]
    const float* __restrict__ w_hh1,  // [256, 64]
    const float* __restrict__ b_ih1,  // [256]
    const float* __restrict__ b_hh1,  // [256]
    const float* __restrict__ fc_w,   // [12, 64]
    const float* __restrict__ fc_b,   // [12]
    float* __restrict__ out)          // [B, 12]
{
    __shared__ float xs[BT][SEQ];    // 8 KB
    __shared__ float h0s[BT][HID];   // 1 KB
    __shared__ float h1s[BT][HID];   // 1 KB
    __shared__ float gs[BT][G4];     // 4 KB

    const int tid = threadIdx.x;
    const int g   = tid;              // gate row owned by this thread
    const int b0  = blockIdx.x * BT;

    // ---- loop-invariant weights: 48 x v4f = 192 VGPRs ----
    v4f w0[16], wi[16], w1[16];
#pragma unroll
    for (int j = 0; j < 16; ++j) w0[j] = ((const v4f*)(w_hh0 + g * HID))[j];
#pragma unroll
    for (int j = 0; j < 16; ++j) wi[j] = ((const v4f*)(w_ih1 + g * HID))[j];
#pragma unroll
    for (int j = 0; j < 16; ++j) w1[j] = ((const v4f*)(w_hh1 + g * HID))[j];
    // PIN: opaque asm def forbids rematerialization (reload-from-global) and
    // makes the allocator actually dedicate VGPRs to these 192 values.
#pragma unroll
    for (int j = 0; j < 16; ++j) {
        asm("" : "+v"(w0[j]));
        asm("" : "+v"(wi[j]));
        asm("" : "+v"(w1[j]));
    }

    const float wih0g = w_ih0[g];                    // input size == 1
    const float bias0 = b_ih0[g] + b_hh0[g];
    const float bias1 = b_ih1[g] + b_hh1[g];

    // ---- stage this block's x tile into LDS ----
    for (int i = tid; i < BT * SEQ; i += 256) {
        int b = i >> 9, t = i & (SEQ - 1);
        xs[b][t] = x[(size_t)(b0 + b) * SEQ + t];
    }
    for (int i = tid; i < BT * HID; i += 256) {
        ((float*)h0s)[i] = 0.f;
        ((float*)h1s)[i] = 0.f;
    }
    const int eb = tid >> 6;     // batch in tile (elementwise phase)
    const int ej = tid & 63;     // hidden unit   (elementwise phase)
    float c0 = 0.f, c1 = 0.f;
    __syncthreads();

    for (int t = 0; t < SEQ; ++t) {
        float a[BT];
        // ===== layer 0: gates0[b][g] = bias0 + x*w_ih0[g] + h0 . w_hh0[g] =====
#pragma unroll
        for (int b = 0; b < BT; ++b) a[b] = fmaf(xs[b][t], wih0g, bias0);
#pragma unroll
        for (int j = 0; j < 16; ++j) {
#pragma unroll
            for (int b = 0; b < BT; ++b) {
                v4f hv = *(const v4f*)&h0s[b][4 * j];   // wave-uniform broadcast
                a[b] = fmaf(hv[0], w0[j][0], a[b]);
                a[b] = fmaf(hv[1], w0[j][1], a[b]);
                a[b] = fmaf(hv[2], w0[j][2], a[b]);
                a[b] = fmaf(hv[3], w0[j][3], a[b]);
            }
        }
#pragma unroll
        for (int b = 0; b < BT; ++b) gs[b][g] = a[b];
        __syncthreads();

        // ===== elementwise 0 (one (b,j) pair per thread; c0 in registers) =====
        {
            float ig = sigf(gs[eb][ej]);
            float fg = sigf(gs[eb][64 + ej]);
            float gg = tanhf_fast(gs[eb][128 + ej]);
            float og = sigf(gs[eb][192 + ej]);
            c0 = fg * c0 + ig * gg;
            h0s[eb][ej] = og * tanhf_fast(c0);
        }
        __syncthreads();

        // ===== layer 1: gates1[b][g] = bias1 + h0_new . w_ih1[g] + h1_old . w_hh1[g] =====
#pragma unroll
        for (int b = 0; b < BT; ++b) a[b] = bias1;
#pragma unroll
        for (int j = 0; j < 16; ++j) {
#pragma unroll
            for (int b = 0; b < BT; ++b) {
                v4f hv  = *(const v4f*)&h0s[b][4 * j];
                v4f h1v = *(const v4f*)&h1s[b][4 * j];
                a[b] = fmaf(hv[0],  wi[j][0], a[b]);
                a[b] = fmaf(hv[1],  wi[j][1], a[b]);
                a[b] = fmaf(hv[2],  wi[j][2], a[b]);
                a[b] = fmaf(hv[3],  wi[j][3], a[b]);
                a[b] = fmaf(h1v[0], w1[j][0], a[b]);
                a[b] = fmaf(h1v[1], w1[j][1], a[b]);
                a[b] = fmaf(h1v[2], w1[j][2], a[b]);
                a[b] = fmaf(h1v[3], w1[j][3], a[b]);
            }
        }
#pragma unroll
        for (int b = 0; b < BT; ++b) gs[b][g] = a[b];
        __syncthreads();

        // ===== elementwise 1 =====
        {
            float ig = sigf(gs[eb][ej]);
            float fg = sigf(gs[eb][64 + ej]);
            float gg = tanhf_fast(gs[eb][128 + ej]);
            float og = sigf(gs[eb][192 + ej]);
            c1 = fg * c1 + ig * gg;
            h1s[eb][ej] = og * tanhf_fast(c1);
        }
        __syncthreads();
    }

    // ===== final projection: out[b][o] = fc_b[o] + h1 . fc_w[o] =====
    if (tid < BT * NOUT) {
        int b = tid / NOUT, o = tid % NOUT;
        float acc = fc_b[o];
#pragma unroll
        for (int j = 0; j < HID; ++j)
            acc = fmaf(fc_w[o * HID + j], h1s[b][j], acc);
        out[(size_t)(b0 + b) * NOUT + o] = acc;
    }
}

extern "C" void kernel_launch(void* const* d_in, const int* in_sizes, int n_in,
                              void* d_out, int out_size, void* d_ws, size_t ws_size,
                              hipStream_t stream) {
    const float* x     = (const float*)d_in[0];
    const float* w_ih0 = (const float*)d_in[1];
    const float* w_hh0 = (const float*)d_in[2];
    const float* b_ih0 = (const float*)d_in[3];
    const float* b_hh0 = (const float*)d_in[4];
    const float* w_ih1 = (const float*)d_in[5];
    const float* w_hh1 = (const float*)d_in[6];
    const float* b_ih1 = (const float*)d_in[7];
    const float* b_hh1 = (const float*)d_in[8];
    const float* fc_w  = (const float*)d_in[9];
    const float* fc_b  = (const float*)d_in[10];

    const int B = in_sizes[0] / SEQ;          // 2048
    dim3 grid(B / BT);                        // 512 blocks -> 2 blocks/CU at 2 waves/EU
    lstm2_fused<<<grid, 256, 0, stream>>>(x, w_ih0, w_hh0, b_ih0, b_hh0,
                                          w_ih1, w_hh1, b_ih1, b_hh1,
                                          fc_w, fc_b, (float*)d_out);
}